// Round 6
// baseline (197.814 us; speedup 1.0000x reference)
//
#include <hip/hip_runtime.h>
#include <hip/hip_bf16.h>

#define N_NODES 50000
#define N_EDGES 800000
#define FEAT 64
#define RANGE 32        // nodes per K2 block
#define NBINS 1563      // ceil(50000/32)
#define K1B 250         // bin blocks; EPB = 3200 (multiple of 4)
#define EPB (N_EDGES / K1B)
#define SUB 8           // slots per (range, bin-block) chunk; fill ~ Poisson(2.05)
#define RSTRIDE 2048    // ent ints per range: 256 padded chunks x 8
#define CAPP 48         // per-node bucket capacity (deg ~ Poisson(16))
#define BSTRIDE 52      // bucket row stride in ints (16B-aligned, odd bank step)
#define DUMMY N_NODES   // zero row index for degree padding
#define CONVB 391       // ceil((N_NODES+1)*FEAT/8 / 1024) conv blocks in fused K01
#define OVF_CAP 16      // per-bin-block overflow capacity
#define PERSIST 1024    // persistent K2 grid: 256 CU x 4 blocks (VGPR 28 -> 4 fit)
#define DIAGX 12        // diagnostic pre-kernel grid multiplier

// ============================================================================
// SESSION LEDGER
//  R2 diag: K01 ~6.3us, K2 ~28.8us (2x: VALU 37%, hbm 30%, occ 69%). Floor ~80.
//  R3 NEUTRAL (118.5): counts8+x4 prefetch. Metadata volume not binding.
//  R4 REGRESSION (138.6): global-atomic CSR. Fabric atomics >> LDS binning.
//  R5 NEUTRAL (117.7): SUB 16->8 (ent halved). ent volume not binding either.
//  R6: (a) PRODUCTION: persistent K2, 1024 blocks + atomic work counter.
//      Occ=69% == 1563/1024 = 1.53 block-waves quantization, exactly. Fix
//      predicts K2 28.8 -> ~21us.
//      (b) DIAGNOSTIC: sort_pre_diag = stage+sort+pad at 12x grid -> top-5
//      rows = 12*pre WITH counters. Splits K2 into pre vs phaseB+epilogue.
//      total ~= 80 + 6.3 + K2p + 12*pre + gaps. Decision: pre<5 -> pipeline
//      phase B deeper; pre>10 -> restructure sort; K2p~29 -> occ model wrong.
// ============================================================================

static __device__ __forceinline__ unsigned short f2bu(float f) {
    __hip_bfloat16 h = __float2bfloat16(f);
    return __builtin_bit_cast(unsigned short, h);
}

// K01: fused conv + bin (16 waves/CU bin part; conv overlaps bin).
__global__ __launch_bounds__(1024) void conv_bin_kernel(
    const float* __restrict__ src_feat,
    unsigned short* __restrict__ src16,
    const int* __restrict__ edge_src,
    const int* __restrict__ edge_dst,
    unsigned char* __restrict__ counts8,  // [K1B][NBINS] u8 (b-major publish)
    int* __restrict__ ent,                // [NBINS][RSTRIDE]; chunk (r,b) at r*2048+b*8
    int2* __restrict__ ovf,               // [K1B][OVF_CAP] (dst, src) pairs
    int* __restrict__ ovfcnt,             // [K1B]
    int* __restrict__ wcnt)               // persistent-K2 work counter
{
    __shared__ int h[NBINS];        // 6.25 KB cursors (bin blocks only)
    __shared__ int ovfc;
    int tid = threadIdx.x;

    if (blockIdx.x < CONVB) {
        if (blockIdx.x == 0 && tid == 0) *wcnt = 0;   // zero before K2 dispatch
        // ---- conv part: 8 floats -> 8 bf16 per thread ----
        int base = (blockIdx.x * 1024 + tid) * 8;
        if (base >= (N_NODES + 1) * FEAT) return;
        uint4 o;
        if (base < N_NODES * FEAT) {
            float4 a = *(const float4*)(src_feat + base);
            float4 b = *(const float4*)(src_feat + base + 4);
            o.x = (unsigned)f2bu(a.x) | ((unsigned)f2bu(a.y) << 16);
            o.y = (unsigned)f2bu(a.z) | ((unsigned)f2bu(a.w) << 16);
            o.z = (unsigned)f2bu(b.x) | ((unsigned)f2bu(b.y) << 16);
            o.w = (unsigned)f2bu(b.z) | ((unsigned)f2bu(b.w) << 16);
        } else {
            o = make_uint4(0, 0, 0, 0);
        }
        *(uint4*)(src16 + base) = o;
        return;
    }

    // ---- bin part: deterministic single-pass binning ----
    int b = blockIdx.x - CONVB;
    for (int r = tid; r < NBINS; r += 1024) h[r] = 0;
    if (tid == 0) ovfc = 0;
    __syncthreads();

    if (tid < EPB / 4) {            // exactly 800 threads, one int4 each
        int e = b * EPB + tid * 4;
        int4 s4 = *(const int4*)(edge_src + e);
        int4 d4 = *(const int4*)(edge_dst + e);
        int r0 = d4.x >> 5, r1 = d4.y >> 5, r2 = d4.z >> 5, r3 = d4.w >> 5;
        int p0 = atomicAdd(&h[r0], 1);
        int p1 = atomicAdd(&h[r1], 1);
        int p2 = atomicAdd(&h[r2], 1);
        int p3 = atomicAdd(&h[r3], 1);
        if (p0 < SUB) ent[r0 * RSTRIDE + b * SUB + p0] = ((d4.x & 31) << 16) | s4.x;
        else { int op = atomicAdd(&ovfc, 1); if (op < OVF_CAP) ovf[b * OVF_CAP + op] = make_int2(d4.x, s4.x); }
        if (p1 < SUB) ent[r1 * RSTRIDE + b * SUB + p1] = ((d4.y & 31) << 16) | s4.y;
        else { int op = atomicAdd(&ovfc, 1); if (op < OVF_CAP) ovf[b * OVF_CAP + op] = make_int2(d4.y, s4.y); }
        if (p2 < SUB) ent[r2 * RSTRIDE + b * SUB + p2] = ((d4.z & 31) << 16) | s4.z;
        else { int op = atomicAdd(&ovfc, 1); if (op < OVF_CAP) ovf[b * OVF_CAP + op] = make_int2(d4.z, s4.z); }
        if (p3 < SUB) ent[r3 * RSTRIDE + b * SUB + p3] = ((d4.w & 31) << 16) | s4.w;
        else { int op = atomicAdd(&ovfc, 1); if (op < OVF_CAP) ovf[b * OVF_CAP + op] = make_int2(d4.w, s4.w); }
    }
    __syncthreads();

    for (int r = tid; r < NBINS; r += 1024) {
        int c = h[r];
        counts8[(size_t)b * NBINS + r] = (unsigned char)((c > SUB) ? SUB : c);
    }
    if (tid == 0) {
        int oc = ovfc;
        ovfcnt[b] = (oc > OVF_CAP) ? OVF_CAP : oc;
    }
}

// Shared phase-A/pre code as a macro-free inline: stage ent+counts, sort
// into buckets, ovf merge, pad. Used by both production K2 and the diag.
#define PRE_BODY(RVAR)                                                        \
    const int* er = ent + (size_t)(RVAR) * RSTRIDE;                           \
    int4 ew = *(const int4*)(er + tid * 4);                                   \
    if (tid < 256) cnt_s[tid] = (tid < K1B) ? (int)counts8[(size_t)tid * NBINS + (RVAR)] : 0; \
    if (tid < RANGE) c[tid] = 0;

#define SORT_BODY(RVAR)                                                       \
    {                                                                         \
        int base_ = tid * 4;                                                  \
        int bb_ = base_ >> 3;                                                 \
        int s0_ = base_ & 7;                                                  \
        int cnt_ = cnt_s[bb_];                                                \
        int vals_[4] = {ew.x, ew.y, ew.z, ew.w};                              \
        _Pragma("unroll")                                                     \
        for (int j_ = 0; j_ < 4; ++j_) {                                      \
            if (s0_ + j_ < cnt_) {                                            \
                int p_ = vals_[j_];                                           \
                int dl_ = p_ >> 16;                                           \
                int pos_ = atomicAdd(&c[dl_], 1);                             \
                if (pos_ < CAPP) bucket_w[dl_ * BSTRIDE + pos_] = p_ & 0xFFFF; \
            }                                                                 \
        }                                                                     \
    }                                                                         \
    if (tid < K1B) {                                                          \
        int oc_ = ovfcnt[tid];                                                \
        for (int e_ = 0; e_ < oc_; ++e_) {                                    \
            int2 pr_ = ovf[tid * OVF_CAP + e_];                               \
            if ((pr_.x >> 5) == (RVAR)) {                                     \
                int dl_ = pr_.x & 31;                                         \
                int pos_ = atomicAdd(&c[dl_], 1);                             \
                if (pos_ < CAPP) bucket_w[dl_ * BSTRIDE + pos_] = pr_.y;      \
            }                                                                 \
        }                                                                     \
    }

#define PAD_BODY                                                              \
    if (tid < RANGE) {                                                        \
        int cc_ = c[tid]; if (cc_ > CAPP) cc_ = CAPP;                         \
        while (cc_ & 3) bucket_w[tid * BSTRIDE + cc_++] = DUMMY;              \
        c[tid] = cc_ >> 2;                                                    \
    }

// Phase-B pipeline macros — all array indices compile-time (rule #20).
#define RDIDX(ID, Q)                                                          \
    _Pragma("unroll")                                                         \
    for (int m_ = 0; m_ < 4; ++m_) {                                          \
        int raw_ = bucket_w[(wave * 4 + m_) * BSTRIDE + (Q) * 4 + sub];       \
        ID[m_] = ((Q) < rows4[m_]) ? raw_ : DUMMY;                            \
    }
#define GLOAD(L, ID)                                                          \
    _Pragma("unroll")                                                         \
    for (int m_ = 0; m_ < 4; ++m_)                                            \
        L[m_] = *(const uint2*)(src16 + (size_t)ID[m_] * FEAT + fc * 4);
#define ACCUM(L)                                                              \
    _Pragma("unroll")                                                         \
    for (int m_ = 0; m_ < 4; ++m_) {                                          \
        acc[m_][0] += __uint_as_float(L[m_].x << 16);                         \
        acc[m_][1] += __uint_as_float(L[m_].x & 0xFFFF0000u);                 \
        acc[m_][2] += __uint_as_float(L[m_].y << 16);                         \
        acc[m_][3] += __uint_as_float(L[m_].y & 0xFFFF0000u);                 \
    }

// K2 PRODUCTION: persistent 1024 blocks, atomic work counter. Per range:
// stage -> sort -> pad -> 2-deep pipelined gather -> butterfly -> 8x8 mm.
__global__ __launch_bounds__(512, 6) void sort_gather_mm_persist(
    const unsigned short* __restrict__ src16,
    const float* __restrict__ dst_feat,
    const unsigned char* __restrict__ counts8,
    const int* __restrict__ ent,
    const int2* __restrict__ ovf,
    const int* __restrict__ ovfcnt,
    int* __restrict__ wcnt,
    float* __restrict__ out)
{
    __shared__ int bucket_w[RANGE * BSTRIDE];   // 6656 B
    __shared__ int cnt_s[256];
    __shared__ int c[RANGE];
    __shared__ int r_s;

    int tid = threadIdx.x;
    int wave = tid >> 6;
    int lane = tid & 63;
    int sub = lane >> 4;
    int fc  = lane & 15;
    int i = lane >> 3;
    int j = lane & 7;

    if (tid == 0) r_s = atomicAdd(wcnt, 1);
    __syncthreads();
    int r = r_s;

    while (r < NBINS) {
        PRE_BODY(r)
        float Bv[4];
        #pragma unroll
        for (int m = 0; m < 4; ++m) {
            int n = r * RANGE + wave * 4 + m;
            Bv[m] = (n < N_NODES) ? dst_feat[n * FEAT + lane] : 0.f;
        }
        __syncthreads();
        SORT_BODY(r)
        __syncthreads();
        PAD_BODY
        __syncthreads();

        int rows4[4], qmax = 0;
        #pragma unroll
        for (int m = 0; m < 4; ++m) {
            rows4[m] = c[wave * 4 + m];
            qmax = (rows4[m] > qmax) ? rows4[m] : qmax;
        }

        float acc[4][4] = {{0.f,0.f,0.f,0.f},{0.f,0.f,0.f,0.f},
                           {0.f,0.f,0.f,0.f},{0.f,0.f,0.f,0.f}};
        {
            int idA[4], idB[4];
            uint2 LA[4], LB[4];
            if (qmax > 0) { RDIDX(idA, 0); GLOAD(LA, idA); }
            int q = 0;
            while (q < qmax) {
                int qn = q + 1;
                if (qn < qmax) { RDIDX(idB, qn); GLOAD(LB, idB); }
                ACCUM(LA);
                q = qn;
                if (q >= qmax) break;
                qn = q + 1;
                if (qn < qmax) { RDIDX(idA, qn); GLOAD(LA, idA); }
                ACCUM(LB);
                q = qn;
            }
        }

        #pragma unroll
        for (int m = 0; m < 4; ++m) {
            #pragma unroll
            for (int u = 0; u < 4; ++u) {
                acc[m][u] += __shfl_xor(acc[m][u], 16, 64);
                acc[m][u] += __shfl_xor(acc[m][u], 32, 64);
            }
        }

        #pragma unroll
        for (int m = 0; m < 4; ++m) {
            int n = r * RANGE + wave * 4 + m;
            if (n >= N_NODES) break;
            float res = 0.0f;
            #pragma unroll
            for (int p = 0; p < 8; ++p) {
                float s_ip = __shfl(acc[m][p & 3], 2 * i + (p >> 2), 64);
                float b_pj = __shfl(Bv[m], p * 8 + j, 64);
                res += s_ip * b_pj;
            }
            out[n * FEAT + lane] = res * 0.35355339059327373f;  // 1/sqrt(8)
        }

        // next range: barrier (all LDS reads done) -> fetch -> barrier
        __syncthreads();
        if (tid == 0) r_s = atomicAdd(wcnt, 1);
        __syncthreads();
        r = r_s;
    }
}

// DIAGNOSTIC: stage+sort+pad ONLY, 12x grid. Digest-write keeps all LDS
// state live (runtime-indexed samples of bucket_w + c). Launched AFTER
// production K2 so cache warming can't flatter the measured dispatch.
__global__ __launch_bounds__(512, 6) void sort_pre_diag(
    const unsigned char* __restrict__ counts8,
    const int* __restrict__ ent,
    const int2* __restrict__ ovf,
    const int* __restrict__ ovfcnt,
    int* __restrict__ diag)
{
    __shared__ int bucket_w[RANGE * BSTRIDE];
    __shared__ int cnt_s[256];
    __shared__ int c[RANGE];

    int r = blockIdx.x % NBINS;
    int tid = threadIdx.x;

    PRE_BODY(r)
    __syncthreads();
    SORT_BODY(r)
    __syncthreads();
    PAD_BODY
    __syncthreads();

    if (tid < 64) {
        int a = c[tid & 31];
        #pragma unroll
        for (int k = 0; k < 8; ++k)
            a ^= bucket_w[tid * 26 + k + (a & 1)];   // runtime index: DCE-proof
        diag[(size_t)blockIdx.x * 64 + tid] = a;
    }
}

extern "C" void kernel_launch(void* const* d_in, const int* in_sizes, int n_in,
                              void* d_out, int out_size, void* d_ws, size_t ws_size,
                              hipStream_t stream) {
    const float* src_feat = (const float*)d_in[0];
    const float* dst_feat = (const float*)d_in[1];
    const int* edge_src = (const int*)d_in[2];
    const int* edge_dst = (const int*)d_in[3];
    float* out = (float*)d_out;

    // ws layout: wcnt    1,024 B
    //            counts8 [K1B][NBINS] u8       =   390,752 B (padded)
    //            ovfcnt  [K1B] ints            =     1,024 B (padded)
    //            ovf     [K1B][OVF_CAP] int2   =    32,000 B
    //            ent     [NBINS][RSTRIDE] ints = 12,804,096 B
    //            src16   (N_NODES+1)*FEAT u16  =  6,400,128 B
    //            diag    18756*64 ints         =  4,801,536 B   (~24.4 MB)
    char* w = (char*)d_ws;
    int* wcnt = (int*)w;                          w += 1024;
    unsigned char* counts8 = (unsigned char*)w;   w += 390752;
    int* ovfcnt = (int*)w;                        w += 1024;
    int2* ovf = (int2*)w;                         w += (size_t)K1B * OVF_CAP * 8;
    int* ent = (int*)w;                           w += (size_t)NBINS * RSTRIDE * 4;
    unsigned short* src16 = (unsigned short*)w;   w += 6400128;
    int* diag = (int*)w;

    conv_bin_kernel<<<CONVB + K1B, 1024, 0, stream>>>(
        src_feat, src16, edge_src, edge_dst, counts8, ent, ovf, ovfcnt, wcnt);

    sort_gather_mm_persist<<<PERSIST, 512, 0, stream>>>(
        src16, dst_feat, counts8, ent, ovf, ovfcnt, wcnt, out);

    sort_pre_diag<<<DIAGX * NBINS, 512, 0, stream>>>(
        counts8, ent, ovf, ovfcnt, diag);
}

// Round 7
// 116.192 us; speedup vs baseline: 1.7025x; 1.7025x over previous
//
#include <hip/hip_runtime.h>
#include <hip/hip_bf16.h>

#define N_NODES 50000
#define N_EDGES 800000
#define FEAT 64
#define RANGE 32        // nodes per K2 block
#define NBINS 1563      // ceil(50000/32)
#define K1B 250         // bin blocks; EPB = 3200 (multiple of 4)
#define EPB (N_EDGES / K1B)
#define SUB 8           // slots per (range, bin-block) chunk; fill ~ Poisson(2.05)
#define RSTRIDE 2048    // ent ints per range: 256 padded chunks x 8
#define CAPP 48         // per-node bucket capacity (deg ~ Poisson(16))
#define BSTRIDE 52      // bucket row stride in ints (16B-aligned, odd bank step)
#define DUMMY N_NODES   // zero row index for degree padding
#define CONVB 391       // ceil((N_NODES+1)*FEAT/8 / 1024) conv blocks in fused K01
#define OVF_CAP 16      // per-bin-block overflow capacity

// ============================================================================
// SESSION LEDGER
//  R2 diag: K01 ~6.3us, K2 ~28.8us (2x: VALU 37%, hbm 30%, occ 69%). Floor ~80.
//  R3 NEUTRAL (118.5): counts8+x4 prefetch. Metadata volume not binding.
//  R4 REGRESSION (138.6): global-atomic CSR. Fabric atomics >> LDS binning.
//  R5 NEUTRAL (117.7): SUB 16->8. ent volume not binding.
//  R6 diag: pre(stage+sort+pad) = 64/12 = 5.3us -> phaseB+epilogue = 23.5us
//     DOMINATES K2. Persistent K2 REGRESSED ~+14us (killed inter-block
//     overlap: strict per-block serialization of ranges + 2 extra barriers).
//  R7: revert to 1563-grid; epilogue bpermutes (96/wave, dominant DS-pipe
//     consumer ~8-9us/CU) -> per-wave LDS staging of S and B; matmul reads
//     are broadcast ds_reads. DS 128->80/wave, no shuffle dep-chains.
//     Predict K2 ~24us, dur ~112.
// ============================================================================

static __device__ __forceinline__ unsigned short f2bu(float f) {
    __hip_bfloat16 h = __float2bfloat16(f);
    return __builtin_bit_cast(unsigned short, h);
}

// K01: fused conv + bin (16 waves/CU bin part; conv overlaps bin).
__global__ __launch_bounds__(1024) void conv_bin_kernel(
    const float* __restrict__ src_feat,
    unsigned short* __restrict__ src16,
    const int* __restrict__ edge_src,
    const int* __restrict__ edge_dst,
    unsigned char* __restrict__ counts8,  // [K1B][NBINS] u8 (b-major publish)
    int* __restrict__ ent,                // [NBINS][RSTRIDE]; chunk (r,b) at r*2048+b*8
    int2* __restrict__ ovf,               // [K1B][OVF_CAP] (dst, src) pairs
    int* __restrict__ ovfcnt)             // [K1B]
{
    __shared__ int h[NBINS];        // 6.25 KB cursors (bin blocks only)
    __shared__ int ovfc;
    int tid = threadIdx.x;

    if (blockIdx.x < CONVB) {
        // ---- conv part: 8 floats -> 8 bf16 per thread ----
        int base = (blockIdx.x * 1024 + tid) * 8;
        if (base >= (N_NODES + 1) * FEAT) return;
        uint4 o;
        if (base < N_NODES * FEAT) {
            float4 a = *(const float4*)(src_feat + base);
            float4 b = *(const float4*)(src_feat + base + 4);
            o.x = (unsigned)f2bu(a.x) | ((unsigned)f2bu(a.y) << 16);
            o.y = (unsigned)f2bu(a.z) | ((unsigned)f2bu(a.w) << 16);
            o.z = (unsigned)f2bu(b.x) | ((unsigned)f2bu(b.y) << 16);
            o.w = (unsigned)f2bu(b.z) | ((unsigned)f2bu(b.w) << 16);
        } else {
            o = make_uint4(0, 0, 0, 0);
        }
        *(uint4*)(src16 + base) = o;
        return;
    }

    // ---- bin part: deterministic single-pass binning ----
    int b = blockIdx.x - CONVB;
    for (int r = tid; r < NBINS; r += 1024) h[r] = 0;
    if (tid == 0) ovfc = 0;
    __syncthreads();

    if (tid < EPB / 4) {            // exactly 800 threads, one int4 each
        int e = b * EPB + tid * 4;
        int4 s4 = *(const int4*)(edge_src + e);
        int4 d4 = *(const int4*)(edge_dst + e);
        int r0 = d4.x >> 5, r1 = d4.y >> 5, r2 = d4.z >> 5, r3 = d4.w >> 5;
        int p0 = atomicAdd(&h[r0], 1);
        int p1 = atomicAdd(&h[r1], 1);
        int p2 = atomicAdd(&h[r2], 1);
        int p3 = atomicAdd(&h[r3], 1);
        if (p0 < SUB) ent[r0 * RSTRIDE + b * SUB + p0] = ((d4.x & 31) << 16) | s4.x;
        else { int op = atomicAdd(&ovfc, 1); if (op < OVF_CAP) ovf[b * OVF_CAP + op] = make_int2(d4.x, s4.x); }
        if (p1 < SUB) ent[r1 * RSTRIDE + b * SUB + p1] = ((d4.y & 31) << 16) | s4.y;
        else { int op = atomicAdd(&ovfc, 1); if (op < OVF_CAP) ovf[b * OVF_CAP + op] = make_int2(d4.y, s4.y); }
        if (p2 < SUB) ent[r2 * RSTRIDE + b * SUB + p2] = ((d4.z & 31) << 16) | s4.z;
        else { int op = atomicAdd(&ovfc, 1); if (op < OVF_CAP) ovf[b * OVF_CAP + op] = make_int2(d4.z, s4.z); }
        if (p3 < SUB) ent[r3 * RSTRIDE + b * SUB + p3] = ((d4.w & 31) << 16) | s4.w;
        else { int op = atomicAdd(&ovfc, 1); if (op < OVF_CAP) ovf[b * OVF_CAP + op] = make_int2(d4.w, s4.w); }
    }
    __syncthreads();

    for (int r = tid; r < NBINS; r += 1024) {
        int c = h[r];
        counts8[(size_t)b * NBINS + r] = (unsigned char)((c > SUB) ? SUB : c);
    }
    if (tid == 0) {
        int oc = ovfc;
        ovfcnt[b] = (oc > OVF_CAP) ? OVF_CAP : oc;
    }
}

// Phase-B pipeline macros — all array indices compile-time (rule #20).
#define RDIDX(ID, Q)                                                          \
    _Pragma("unroll")                                                         \
    for (int m_ = 0; m_ < 4; ++m_) {                                          \
        int raw_ = bucket_w[(wave * 4 + m_) * BSTRIDE + (Q) * 4 + sub];       \
        ID[m_] = ((Q) < rows4[m_]) ? raw_ : DUMMY;                            \
    }
#define GLOAD(L, ID)                                                          \
    _Pragma("unroll")                                                         \
    for (int m_ = 0; m_ < 4; ++m_)                                            \
        L[m_] = *(const uint2*)(src16 + (size_t)ID[m_] * FEAT + fc * 4);
#define ACCUM(L)                                                              \
    _Pragma("unroll")                                                         \
    for (int m_ = 0; m_ < 4; ++m_) {                                          \
        acc[m_][0] += __uint_as_float(L[m_].x << 16);                         \
        acc[m_][1] += __uint_as_float(L[m_].x & 0xFFFF0000u);                 \
        acc[m_][2] += __uint_as_float(L[m_].y << 16);                         \
        acc[m_][3] += __uint_as_float(L[m_].y & 0xFFFF0000u);                 \
    }

// K2: stage -> sort -> pad -> 2-deep pipelined gather -> butterfly ->
// LDS-staged 8x8 matmul (NO bpermutes in epilogue — R7 change).
__global__ __launch_bounds__(512, 6) void sort_gather_mm_kernel(
    const unsigned short* __restrict__ src16,
    const float* __restrict__ dst_feat,
    const unsigned char* __restrict__ counts8,
    const int* __restrict__ ent,
    const int2* __restrict__ ovf,
    const int* __restrict__ ovfcnt,
    float* __restrict__ out)
{
    __shared__ int bucket_w[RANGE * BSTRIDE];   // 6656 B
    __shared__ int cnt_s[256];                  // 250 real + 6 zero pads
    __shared__ int c[RANGE];
    __shared__ float4 S_lds[RANGE * 16];        // 8 KB: [node][fc] = S feats fc*4..+3
    __shared__ float B_lds[RANGE][FEAT];        // 8 KB: [node][p*8+j] = B[p][j]

    int r = blockIdx.x;
    int tid = threadIdx.x;
    int wave = tid >> 6;
    int lane = tid & 63;

    // Unconditional ent prefetch: ONE dwordx4 per thread (2048 slots total).
    const int* er = ent + (size_t)r * RSTRIDE;
    int4 ew = *(const int4*)(er + tid * 4);

    // counts: 250 scattered BYTE reads, L2/L3-line-shared across 64 r-blocks.
    if (tid < 256) cnt_s[tid] = (tid < K1B) ? (int)counts8[(size_t)tid * NBINS + r] : 0;
    if (tid < RANGE) c[tid] = 0;

    // dst rows -> per-wave-private B_lds. The ds_write is free latency-wise:
    // the first __syncthreads would force vmcnt(0) on these loads anyway.
    #pragma unroll
    for (int m = 0; m < 4; ++m) {
        int n = r * RANGE + wave * 4 + m;
        float bv = (n < N_NODES) ? dst_feat[n * FEAT + lane] : 0.f;
        B_lds[wave * 4 + m][lane] = bv;
    }
    __syncthreads();

    // Phase A: filter prefetched slots, sort into per-node u32 buckets.
    {
        int base = tid * 4;
        int bb = base >> 3;           // chunk index (uniform over the quad)
        int s0 = base & 7;            // 0 or 4
        int cnt = cnt_s[bb];
        int vals[4] = {ew.x, ew.y, ew.z, ew.w};
        #pragma unroll
        for (int j = 0; j < 4; ++j) {
            if (s0 + j < cnt) {
                int p = vals[j];
                int dl = p >> 16;
                int pos = atomicAdd(&c[dl], 1);
                if (pos < CAPP) bucket_w[dl * BSTRIDE + pos] = p & 0xFFFF;
            }
        }
    }
    // Rare overflow merge: 250 contiguous counts, almost always zero.
    if (tid < K1B) {
        int oc = ovfcnt[tid];
        for (int e = 0; e < oc; ++e) {
            int2 pr = ovf[tid * OVF_CAP + e];
            if ((pr.x >> 5) == r) {
                int dl = pr.x & 31;
                int pos = atomicAdd(&c[dl], 1);
                if (pos < CAPP) bucket_w[dl * BSTRIDE + pos] = pr.y;
            }
        }
    }
    __syncthreads();

    // Pad each node's count to a multiple of 4 with the zero dummy row.
    if (tid < RANGE) {
        int cc = c[tid]; if (cc > CAPP) cc = CAPP;
        while (cc & 3) bucket_w[tid * BSTRIDE + cc++] = DUMMY;
        c[tid] = cc >> 2;             // rows-of-4 count
    }
    __syncthreads();

    // Phase B: wide gather, 2-deep pipelined. Lane covers row-slot (lane>>4),
    // features (lane&15)*4. One dwordx2 load = 4 rows x 128B per wave-instr.
    int sub = lane >> 4;
    int fc  = lane & 15;
    int rows4[4], qmax = 0;
    #pragma unroll
    for (int m = 0; m < 4; ++m) {
        rows4[m] = c[wave * 4 + m];
        qmax = (rows4[m] > qmax) ? rows4[m] : qmax;
    }

    float acc[4][4] = {{0.f,0.f,0.f,0.f},{0.f,0.f,0.f,0.f},
                       {0.f,0.f,0.f,0.f},{0.f,0.f,0.f,0.f}};
    {
        int idA[4], idB[4];
        uint2 LA[4], LB[4];
        if (qmax > 0) { RDIDX(idA, 0); GLOAD(LA, idA); }
        int q = 0;
        while (q < qmax) {           // qmax wave-uniform -> no divergence
            int qn = q + 1;
            if (qn < qmax) { RDIDX(idB, qn); GLOAD(LB, idB); }
            ACCUM(LA);
            q = qn;
            if (q >= qmax) break;
            qn = q + 1;
            if (qn < qmax) { RDIDX(idA, qn); GLOAD(LA, idA); }
            ACCUM(LB);
            q = qn;
        }
    }

    // Butterfly-reduce the 4 row-slots: all lanes end with full sums for
    // features fc*4+u of node m.
    #pragma unroll
    for (int m = 0; m < 4; ++m) {
        #pragma unroll
        for (int u = 0; u < 4; ++u) {
            acc[m][u] += __shfl_xor(acc[m][u], 16, 64);
            acc[m][u] += __shfl_xor(acc[m][u], 32, 64);
        }
    }

    // Stage S into per-wave-private LDS (lanes 0-15 carry sub==0 copies).
    // Same-wave RAW only -> no barrier, compiler inserts lgkmcnt.
    if (lane < 16) {
        #pragma unroll
        for (int m = 0; m < 4; ++m)
            S_lds[(wave * 4 + m) * 16 + fc] =
                make_float4(acc[m][0], acc[m][1], acc[m][2], acc[m][3]);
    }

    // Epilogue: 8x8 matmul from LDS, zero bpermutes. Lane (i,j):
    // res = sum_p S[i][p] * B[p][j]; S row = 2 float4s, B col = 8 b32
    // broadcast reads.
    int i = lane >> 3;
    int j = lane & 7;
    #pragma unroll
    for (int m = 0; m < 4; ++m) {
        int n = r * RANGE + wave * 4 + m;
        if (n >= N_NODES) break;
        int node = wave * 4 + m;
        float4 s0 = S_lds[node * 16 + 2 * i];
        float4 s1 = S_lds[node * 16 + 2 * i + 1];
        const float* Bc = &B_lds[node][j];
        float res = s0.x * Bc[0]  + s0.y * Bc[8]  + s0.z * Bc[16] + s0.w * Bc[24]
                  + s1.x * Bc[32] + s1.y * Bc[40] + s1.z * Bc[48] + s1.w * Bc[56];
        out[n * FEAT + lane] = res * 0.35355339059327373f;  // 1/sqrt(8)
    }
}

extern "C" void kernel_launch(void* const* d_in, const int* in_sizes, int n_in,
                              void* d_out, int out_size, void* d_ws, size_t ws_size,
                              hipStream_t stream) {
    const float* src_feat = (const float*)d_in[0];
    const float* dst_feat = (const float*)d_in[1];
    const int* edge_src = (const int*)d_in[2];
    const int* edge_dst = (const int*)d_in[3];
    float* out = (float*)d_out;

    // ws layout: counts8 [K1B][NBINS] u8       =   390,752 B (padded)
    //            ovfcnt  [K1B] ints            =     1,024 B (padded)
    //            ovf     [K1B][OVF_CAP] int2   =    32,000 B
    //            ent     [NBINS][RSTRIDE] ints = 12,804,096 B
    //            src16   (N_NODES+1)*FEAT u16  =  6,400,128 B   (~19.6 MB)
    char* w = (char*)d_ws;
    unsigned char* counts8 = (unsigned char*)w;   w += 390752;
    int* ovfcnt = (int*)w;                        w += 1024;
    int2* ovf = (int2*)w;                         w += (size_t)K1B * OVF_CAP * 8;
    int* ent = (int*)w;                           w += (size_t)NBINS * RSTRIDE * 4;
    unsigned short* src16 = (unsigned short*)w;

    conv_bin_kernel<<<CONVB + K1B, 1024, 0, stream>>>(
        src_feat, src16, edge_src, edge_dst, counts8, ent, ovf, ovfcnt);

    sort_gather_mm_kernel<<<NBINS, 512, 0, stream>>>(
        src16, dst_feat, counts8, ent, ovf, ovfcnt, out);
}